// Round 8
// baseline (151.279 us; speedup 1.0000x reference)
//
#include <hip/hip_runtime.h>

#define BATCH 524288

typedef __bf16 bf16x8 __attribute__((ext_vector_type(8)));
typedef __bf16 bf16x2 __attribute__((ext_vector_type(2)));
typedef float f32x4 __attribute__((ext_vector_type(4)));
typedef float f32x8 __attribute__((ext_vector_type(8)));
typedef float f32x2 __attribute__((ext_vector_type(2)));

// LDS layout:
//   sA2  @     0: 16384 B  A2 in MFMA-A frag order (v5-verified)
//   sW1f @ 16384:  4096 B  W1 identity copy + 32 B zero chunk @ 20480
//   sW2f @ 20512:  8192 B  W2 in PERMUTED frag order (hidden k-in-slice = 2c+(t&1)):
//                  chunk(t2,s)=t2*4+s; lane(c,q) b32 j2 -> (W2[..][s*32+4q+j2], W2[..][s*32+16+4q+j2])
//   hcw  @ 28704 + wave*2560 + t01*1280: 16 rows x 40 bf16 (stride 80 B: packed b32
//                  writes land exactly 2 lanes/bank = conflict-free; b128 reads aligned)
#define SMEM_BYTES (28704 + 4 * 2560)   // 38944 B -> 4 blocks/CU by LDS

__device__ __forceinline__ f32x8 load8(const float* __restrict__ p) {
    float4 a = *(const float4*)p;
    float4 b = *(const float4*)(p + 4);
    f32x8 v = {a.x, a.y, a.z, a.w, b.x, b.y, b.z, b.w};
    return v;
}

__device__ __forceinline__ int pack2bf(float a, float b) {
    f32x2 v = {a, b};
    bf16x2 p = __builtin_convertvector(v, bf16x2);
    return __builtin_bit_cast(int, p);
}

__global__ __launch_bounds__(256, 4) void andp_v8(
    const float* __restrict__ x_cur,
    const float* __restrict__ W1,
    const float* __restrict__ b1,
    const float* __restrict__ W2,
    const float* __restrict__ b2,
    const float* __restrict__ Bm,
    const float* __restrict__ Cm,
    const float* __restrict__ x_t,
    float* __restrict__ out)
{
    extern __shared__ char smem[];
    int* sA2i = (int*)smem;
    int* sW1i = (int*)(smem + 16384);
    int* sW2i = (int*)(smem + 20512);
    const int tid = threadIdx.x;

    // ---- stage A2 = Bm + Cm into frag order (v5-verified) ----
#pragma unroll
    for (int i = 0; i < 16; ++i) {
        int o2 = tid + i * 256;
        int o  = o2 * 2;
        int kk = o >> 9, k = (o >> 5) & 15, qp = (o >> 3) & 3, j = o & 7;
        int n = 2 * kk + (qp >> 1), d = (qp & 1) * 8 + j;
        int src = n * 256 + k * 16 + d;
        float2 bv = *(const float2*)(Bm + src);
        float2 cv = *(const float2*)(Cm + src);
        sA2i[o2] = pack2bf(bv.x + cv.x, bv.y + cv.y);
    }
    // ---- stage W1 (identity frag order) + zero chunk (v5-verified) ----
#pragma unroll
    for (int i = 0; i < 4; ++i) {
        int p0 = tid + i * 256;
        float2 v = *(const float2*)(W1 + 2 * p0);
        sW1i[p0] = pack2bf(v.x, v.y);
    }
    if (tid < 8) sW1i[1024 + tid] = 0;
    // ---- stage W2 in permuted frag order ----
#pragma unroll
    for (int i = 0; i < 8; ++i) {
        int o2 = tid + i * 256;                 // b32 index 0..2047
        int chunk = o2 >> 8, rem = o2 & 255;
        int ln = rem >> 2, j2 = rem & 3;
        int qq = ln >> 4, cc = ln & 15;
        int t2 = chunk >> 2, s = chunk & 3;
        int src = (t2 * 16 + cc) * 128 + s * 32 + 4 * qq + j2;
        sW2i[o2] = pack2bf(W2[src], W2[src + 16]);   // elems (j=2*j2, j=2*j2+1)
    }

    const int wave = tid >> 6, lane = tid & 63;
    const int c = lane & 15, q = lane >> 4;
    const int qh = q >> 1;                       // n parity for G3
    const int hh = (q & 1) * 8;                  // d-half this lane owns
    const int c4 = c * 4;

    const char* sW1f = smem + 16384;
    const int w1base = (q < 2) ? (c * 32 + q * 16) : 4096;
    const int w1step = (q < 2) ? 512 : 0;
    const char* sW2f = smem + 20512 + lane * 16;        // + chunk*1024
    __bf16* hcw0 = (__bf16*)(smem + 28704 + wave * 2560);
    __bf16* hcw1 = hcw0 + 640;

    // ---- register-resident constants ----
    float b1v[8];
#pragma unroll
    for (int t = 0; t < 8; ++t) b1v[t] = b1[t * 16 + c];
    float b2v[2][4];
#pragma unroll
    for (int t2 = 0; t2 < 2; ++t2)
#pragma unroll
        for (int r = 0; r < 4; ++r) b2v[t2][r] = b2[t2 * 16 + q * 4 + r];
    const f32x8 xtv = load8(x_t + hh);

    __syncthreads();

    const int blk_row = blockIdx.x * 256 + wave * 64;
    const f32x4 z4 = {0.f, 0.f, 0.f, 0.f};

    // ---- both pairs' x upfront: global latency off the critical path ----
    f32x8 xv[2][2];
#pragma unroll
    for (int p = 0; p < 2; ++p)
#pragma unroll
        for (int t01 = 0; t01 < 2; ++t01)
            xv[p][t01] = load8(x_cur + (size_t)(blk_row + p * 32 + t01 * 16 + c) * 16 + hh);

#pragma unroll 1
    for (int p = 0; p < 2; ++p) {
        const int r0 = blk_row + p * 32;

        bf16x8 af[2];
        f32x8 dif[2];
#pragma unroll
        for (int t01 = 0; t01 < 2; ++t01) {
            af[t01]  = __builtin_convertvector(xv[p][t01], bf16x8);
            dif[t01] = xtv - xv[p][t01];
        }

        // ---- fused G1/G2, t01-interleaved for ILP on the LDS chain ----
        f32x4 acc2[2][2];
        acc2[0][0] = z4; acc2[0][1] = z4; acc2[1][0] = z4; acc2[1][1] = z4;
#pragma unroll
        for (int s = 0; s < 4; ++s) {
#pragma unroll
            for (int t01 = 0; t01 < 2; ++t01) {
                __bf16* hcw = t01 ? hcw1 : hcw0;
                bf16x8 w1a = *(const bf16x8*)(sW1f + w1base + (2 * s) * w1step);
                bf16x8 w1b = *(const bf16x8*)(sW1f + w1base + (2 * s + 1) * w1step);
                f32x4 a1a = __builtin_amdgcn_mfma_f32_16x16x32_bf16(af[t01], w1a, z4, 0, 0, 0);
                f32x4 a1b = __builtin_amdgcn_mfma_f32_16x16x32_bf16(af[t01], w1b, z4, 0, 0, 0);
                // packed epilogue: k-in-slice = 2c (t=2s) and 2c+1 (t=2s+1) -> one b32
#pragma unroll
                for (int r = 0; r < 4; ++r) {
                    float va = fmaxf(a1a[r] + b1v[2 * s], 0.f);
                    float vb = fmaxf(a1b[r] + b1v[2 * s + 1], 0.f);
                    *(int*)(hcw + (q * 4 + r) * 40 + 2 * c) = pack2bf(va, vb);
                }
            }
#pragma unroll
            for (int t01 = 0; t01 < 2; ++t01) {
                __bf16* hcw = t01 ? hcw1 : hcw0;
                bf16x8 hb = *(const bf16x8*)(hcw + c * 40 + q * 8);
                bf16x8 w20 = *(const bf16x8*)(sW2f + (0 * 4 + s) * 1024);
                bf16x8 w21 = *(const bf16x8*)(sW2f + (1 * 4 + s) * 1024);
                acc2[t01][0] = __builtin_amdgcn_mfma_f32_16x16x32_bf16(w20, hb, acc2[t01][0], 0, 0, 0);
                acc2[t01][1] = __builtin_amdgcn_mfma_f32_16x16x32_bf16(w21, hb, acc2[t01][1], 0, 0, 0);
            }
        }

        // ---- softmax (no max-sub: |logits| small by construction); pack t01-pairs ----
        int wq[8];       // wq[t2*4+r] = bf16x2 (lo = t01_0, hi = t01_1) for n = t2*16+q*4+r
        float w0f[8];
#pragma unroll
        for (int t01 = 0; t01 < 2; ++t01) {
            float e[8], sum = 0.f;
#pragma unroll
            for (int t2 = 0; t2 < 2; ++t2)
#pragma unroll
                for (int r = 0; r < 4; ++r) {
                    e[t2 * 4 + r] = __expf(acc2[t01][t2][r] + b2v[t2][r]);
                    sum += e[t2 * 4 + r];
                }
            sum += __shfl_xor(sum, 16, 64);
            sum += __shfl_xor(sum, 32, 64);
            float inv = 1.0f / sum;
            if (t01 == 0) {
#pragma unroll
                for (int i = 0; i < 8; ++i) w0f[i] = e[i] * inv;
            } else {
#pragma unroll
                for (int i = 0; i < 8; ++i) wq[i] = pack2bf(w0f[i], e[i] * inv);
            }
        }

        // ---- G3 (transposed, v5-verified core): outT = A2 @ G^T, K=512 ----
        // FIX vs v7: bpermute operands are register-index-UNIFORM (wq[lo], wq[lo+1]);
        // the qh-dependent r-parity selection happens POST-permute on received values.
        f32x4 acc3[2];
        acc3[0] = z4; acc3[1] = z4;
#pragma unroll
        for (int kk = 0; kk < 16; ++kk) {
            const int lo = (kk >> 3) * 4 + 2 * (kk & 1);
            const int bpi = c4 + ((kk >> 1) & 3) * 64;
            int bpA = __builtin_amdgcn_ds_bpermute(bpi, wq[lo]);      // n = 2kk
            int bpB = __builtin_amdgcn_ds_bpermute(bpi, wq[lo + 1]);  // n = 2kk+1
            int sel = qh ? bpB : bpA;                                  // n = 2kk+qh
            float w0 = __builtin_bit_cast(float, (unsigned)sel << 16);
            float w1 = __builtin_bit_cast(float, (unsigned)sel & 0xffff0000u);
            bf16x8 a2f = *(const bf16x8*)(smem + kk * 1024 + (c * 4 + q) * 16);
            bf16x8 g0 = __builtin_convertvector(dif[0] * w0, bf16x8);
            bf16x8 g1 = __builtin_convertvector(dif[1] * w1, bf16x8);
            acc3[0] = __builtin_amdgcn_mfma_f32_16x16x32_bf16(a2f, g0, acc3[0], 0, 0, 0);
            acc3[1] = __builtin_amdgcn_mfma_f32_16x16x32_bf16(a2f, g1, acc3[1], 0, 0, 0);
        }

        // ---- store: D[m=k_out=q*4+r][n=row=c] -> float4 per tile ----
#pragma unroll
        for (int t01 = 0; t01 < 2; ++t01) {
            float4 st = make_float4(acc3[t01][0], acc3[t01][1], acc3[t01][2], acc3[t01][3]);
            *(float4*)(out + (size_t)(r0 + t01 * 16 + c) * 16 + q * 4) = st;
        }
    }
}

extern "C" void kernel_launch(void* const* d_in, const int* in_sizes, int n_in,
                              void* d_out, int out_size, void* d_ws, size_t ws_size,
                              hipStream_t stream) {
    const float* x_cur = (const float*)d_in[0];
    const float* W1    = (const float*)d_in[1];
    const float* b1    = (const float*)d_in[2];
    const float* W2    = (const float*)d_in[3];
    const float* b2    = (const float*)d_in[4];
    const float* Bm    = (const float*)d_in[5];
    const float* Cm    = (const float*)d_in[6];
    const float* x_t   = (const float*)d_in[7];
    float* out = (float*)d_out;

    const int blocks = BATCH / 256;   // 2048 blocks x 256 rows
    andp_v8<<<blocks, 256, SMEM_BYTES, stream>>>(
        x_cur, W1, b1, W2, b2, Bm, Cm, x_t, out);
}

// Round 9
// 132.065 us; speedup vs baseline: 1.1455x; 1.1455x over previous
//
#include <hip/hip_runtime.h>

#define BATCH 524288

typedef __bf16 bf16x8 __attribute__((ext_vector_type(8)));
typedef __bf16 bf16x2 __attribute__((ext_vector_type(2)));
typedef float f32x4 __attribute__((ext_vector_type(4)));
typedef float f32x8 __attribute__((ext_vector_type(8)));
typedef float f32x2 __attribute__((ext_vector_type(2)));

// LDS layout:
//   sA2  @     0: 16384 B  A2 in MFMA-A frag order (v5-verified)
//   sW1f @ 16384:  4096 B  W1 identity copy + 32 B zero chunk @ 20480
//   sW2f @ 20512:  8192 B  W2 in PERMUTED frag order (hidden k-in-slice = 2c+(t&1))
//   hcw  @ 28704 + wave*2560 + t01*1280: 16 rows x 40 bf16 (packed b32 writes:
//                  exactly 2 lanes/bank = conflict-free; b128 reads aligned)
#define SMEM_BYTES (28704 + 4 * 2560)   // 38944 B -> 4 blocks/CU by LDS

__device__ __forceinline__ f32x8 load8(const float* __restrict__ p) {
    float4 a = *(const float4*)p;
    float4 b = *(const float4*)(p + 4);
    f32x8 v = {a.x, a.y, a.z, a.w, b.x, b.y, b.z, b.w};
    return v;
}

__device__ __forceinline__ int pack2bf(float a, float b) {
    f32x2 v = {a, b};
    bf16x2 p = __builtin_convertvector(v, bf16x2);
    return __builtin_bit_cast(int, p);
}

__global__ __launch_bounds__(256, 4) void andp_v9(
    const float* __restrict__ x_cur,
    const float* __restrict__ W1,
    const float* __restrict__ b1,
    const float* __restrict__ W2,
    const float* __restrict__ b2,
    const float* __restrict__ Bm,
    const float* __restrict__ Cm,
    const float* __restrict__ x_t,
    float* __restrict__ out)
{
    extern __shared__ char smem[];
    int* sA2i = (int*)smem;
    int* sW1i = (int*)(smem + 16384);
    int* sW2i = (int*)(smem + 20512);
    const int tid = threadIdx.x;

    // ---- stage A2 = Bm + Cm into frag order (v5-verified) ----
#pragma unroll
    for (int i = 0; i < 16; ++i) {
        int o2 = tid + i * 256;
        int o  = o2 * 2;
        int kk = o >> 9, k = (o >> 5) & 15, qp = (o >> 3) & 3, j = o & 7;
        int n = 2 * kk + (qp >> 1), d = (qp & 1) * 8 + j;
        int src = n * 256 + k * 16 + d;
        float2 bv = *(const float2*)(Bm + src);
        float2 cv = *(const float2*)(Cm + src);
        sA2i[o2] = pack2bf(bv.x + cv.x, bv.y + cv.y);
    }
    // ---- stage W1 (identity frag order) + zero chunk ----
#pragma unroll
    for (int i = 0; i < 4; ++i) {
        int p0 = tid + i * 256;
        float2 v = *(const float2*)(W1 + 2 * p0);
        sW1i[p0] = pack2bf(v.x, v.y);
    }
    if (tid < 8) sW1i[1024 + tid] = 0;
    // ---- stage W2 in permuted frag order ----
#pragma unroll
    for (int i = 0; i < 8; ++i) {
        int o2 = tid + i * 256;
        int chunk = o2 >> 8, rem = o2 & 255;
        int ln = rem >> 2, j2 = rem & 3;
        int qq = ln >> 4, cc = ln & 15;
        int t2 = chunk >> 2, s = chunk & 3;
        int src = (t2 * 16 + cc) * 128 + s * 32 + 4 * qq + j2;
        sW2i[o2] = pack2bf(W2[src], W2[src + 16]);
    }

    const int wave = tid >> 6, lane = tid & 63;
    const int c = lane & 15, q = lane >> 4;
    const int qh = q >> 1;                       // n parity for G3
    const int hh = (q & 1) * 8;                  // d-half this lane owns
    const int c4 = c * 4;

    const char* sW1f = smem + 16384;
    const int w1base = (q < 2) ? (c * 32 + q * 16) : 4096;
    const int w1step = (q < 2) ? 512 : 0;
    const char* sW2f = smem + 20512 + lane * 16;        // + chunk*1024
    __bf16* hcw0 = (__bf16*)(smem + 28704 + wave * 2560);
    __bf16* hcw1 = hcw0 + 640;

    // ---- register-resident constants ----
    float b1v[8];
#pragma unroll
    for (int t = 0; t < 8; ++t) b1v[t] = b1[t * 16 + c];
    float b2v[2][4];
#pragma unroll
    for (int t2 = 0; t2 < 2; ++t2)
#pragma unroll
        for (int r = 0; r < 4; ++r) b2v[t2][r] = b2[t2 * 16 + q * 4 + r];
    const f32x8 xtv = load8(x_t + hh);

    __syncthreads();

    const int blk_row = blockIdx.x * 256 + wave * 64;
    const f32x4 z4 = {0.f, 0.f, 0.f, 0.f};

#pragma unroll 1
    for (int p = 0; p < 2; ++p) {
        const int r0 = blk_row + p * 32;

        // ---- x from global, per-pair (fits the 128-reg budget) ----
        bf16x8 af[2];
        f32x8 dif[2];
#pragma unroll
        for (int t01 = 0; t01 < 2; ++t01) {
            f32x8 xv = load8(x_cur + (size_t)(r0 + t01 * 16 + c) * 16 + hh);
            af[t01]  = __builtin_convertvector(xv, bf16x8);
            dif[t01] = xtv - xv;
        }

        // ---- fused G1/G2, t01-interleaved for ILP on the LDS chain ----
        f32x4 acc2[2][2];
        acc2[0][0] = z4; acc2[0][1] = z4; acc2[1][0] = z4; acc2[1][1] = z4;
#pragma unroll
        for (int s = 0; s < 4; ++s) {
#pragma unroll
            for (int t01 = 0; t01 < 2; ++t01) {
                __bf16* hcw = t01 ? hcw1 : hcw0;
                bf16x8 w1a = *(const bf16x8*)(sW1f + w1base + (2 * s) * w1step);
                bf16x8 w1b = *(const bf16x8*)(sW1f + w1base + (2 * s + 1) * w1step);
                f32x4 a1a = __builtin_amdgcn_mfma_f32_16x16x32_bf16(af[t01], w1a, z4, 0, 0, 0);
                f32x4 a1b = __builtin_amdgcn_mfma_f32_16x16x32_bf16(af[t01], w1b, z4, 0, 0, 0);
                // packed epilogue: k-in-slice = 2c (t=2s), 2c+1 (t=2s+1) -> one b32
#pragma unroll
                for (int r = 0; r < 4; ++r) {
                    float va = fmaxf(a1a[r] + b1v[2 * s], 0.f);
                    float vb = fmaxf(a1b[r] + b1v[2 * s + 1], 0.f);
                    *(int*)(hcw + (q * 4 + r) * 40 + 2 * c) = pack2bf(va, vb);
                }
            }
#pragma unroll
            for (int t01 = 0; t01 < 2; ++t01) {
                __bf16* hcw = t01 ? hcw1 : hcw0;
                bf16x8 hb = *(const bf16x8*)(hcw + c * 40 + q * 8);
                bf16x8 w20 = *(const bf16x8*)(sW2f + (0 * 4 + s) * 1024);
                bf16x8 w21 = *(const bf16x8*)(sW2f + (1 * 4 + s) * 1024);
                acc2[t01][0] = __builtin_amdgcn_mfma_f32_16x16x32_bf16(w20, hb, acc2[t01][0], 0, 0, 0);
                acc2[t01][1] = __builtin_amdgcn_mfma_f32_16x16x32_bf16(w21, hb, acc2[t01][1], 0, 0, 0);
            }
        }

        // ---- softmax (no max-sub: |logits| small by construction) ----
        // wq[t2*4+r] = bf16x2 (lo = t01_0, hi = t01_1) for n = t2*16+q*4+r,
        // built by OR-merge (no float staging array -> 8 fewer live regs).
        int wq[8];
#pragma unroll
        for (int t01 = 0; t01 < 2; ++t01) {
            float e[8], sum = 0.f;
#pragma unroll
            for (int t2 = 0; t2 < 2; ++t2)
#pragma unroll
                for (int r = 0; r < 4; ++r) {
                    e[t2 * 4 + r] = __expf(acc2[t01][t2][r] + b2v[t2][r]);
                    sum += e[t2 * 4 + r];
                }
            sum += __shfl_xor(sum, 16, 64);
            sum += __shfl_xor(sum, 32, 64);
            float inv = 1.0f / sum;
            if (t01 == 0) {
#pragma unroll
                for (int i = 0; i < 8; ++i) wq[i] = pack2bf(e[i] * inv, 0.f);
            } else {
#pragma unroll
                for (int i = 0; i < 8; ++i) wq[i] |= pack2bf(0.f, e[i] * inv);
            }
        }

        // ---- G3 (v8-verified): bpermute on register-index-UNIFORM operands,
        // qh parity selected post-permute ----
        f32x4 acc3[2];
        acc3[0] = z4; acc3[1] = z4;
#pragma unroll
        for (int kk = 0; kk < 16; ++kk) {
            const int lo = (kk >> 3) * 4 + 2 * (kk & 1);
            const int bpi = c4 + ((kk >> 1) & 3) * 64;
            int bpA = __builtin_amdgcn_ds_bpermute(bpi, wq[lo]);      // n = 2kk
            int bpB = __builtin_amdgcn_ds_bpermute(bpi, wq[lo + 1]);  // n = 2kk+1
            int sel = qh ? bpB : bpA;                                  // n = 2kk+qh
            float w0 = __builtin_bit_cast(float, (unsigned)sel << 16);
            float w1 = __builtin_bit_cast(float, (unsigned)sel & 0xffff0000u);
            bf16x8 a2f = *(const bf16x8*)(smem + kk * 1024 + (c * 4 + q) * 16);
            bf16x8 g0 = __builtin_convertvector(dif[0] * w0, bf16x8);
            bf16x8 g1 = __builtin_convertvector(dif[1] * w1, bf16x8);
            acc3[0] = __builtin_amdgcn_mfma_f32_16x16x32_bf16(a2f, g0, acc3[0], 0, 0, 0);
            acc3[1] = __builtin_amdgcn_mfma_f32_16x16x32_bf16(a2f, g1, acc3[1], 0, 0, 0);
        }

        // ---- store: D[m=k_out=q*4+r][n=row=c] -> float4 per tile ----
#pragma unroll
        for (int t01 = 0; t01 < 2; ++t01) {
            float4 st = make_float4(acc3[t01][0], acc3[t01][1], acc3[t01][2], acc3[t01][3]);
            *(float4*)(out + (size_t)(r0 + t01 * 16 + c) * 16 + q * 4) = st;
        }
    }
}

extern "C" void kernel_launch(void* const* d_in, const int* in_sizes, int n_in,
                              void* d_out, int out_size, void* d_ws, size_t ws_size,
                              hipStream_t stream) {
    const float* x_cur = (const float*)d_in[0];
    const float* W1    = (const float*)d_in[1];
    const float* b1    = (const float*)d_in[2];
    const float* W2    = (const float*)d_in[3];
    const float* b2    = (const float*)d_in[4];
    const float* Bm    = (const float*)d_in[5];
    const float* Cm    = (const float*)d_in[6];
    const float* x_t   = (const float*)d_in[7];
    float* out = (float*)d_out;

    const int blocks = BATCH / 256;   // 2048 blocks x 256 rows
    andp_v9<<<blocks, 256, SMEM_BYTES, stream>>>(
        x_cur, W1, b1, W2, b2, Bm, Cm, x_t, out);
}

// Round 10
// 119.450 us; speedup vs baseline: 1.2665x; 1.1056x over previous
//
#include <hip/hip_runtime.h>

#define BATCH 524288

typedef __bf16 bf16x8 __attribute__((ext_vector_type(8)));
typedef __bf16 bf16x2 __attribute__((ext_vector_type(2)));
typedef float f32x4 __attribute__((ext_vector_type(4)));
typedef float f32x8 __attribute__((ext_vector_type(8)));
typedef float f32x2 __attribute__((ext_vector_type(2)));

// LDS layout (all fragment reads are lane-consecutive 16B chunks = conflict-free):
//   sA2  @     0: 16384 B  A2, chunk(kk, lane)=kk*1024+lane*16; lane(c,q) elems j ->
//                          A[n=2kk+(q>>1)][k_out=c][d=(q&1)*8+j]
//   sW1f @ 16384:  4096 B  W1 frags, chunk(t, q*16+c) for q<2; +32 B zero chunk @ 20480
//   sW2f @ 20512:  8192 B  W2 permuted frags (v9-verified), chunk(t2*4+s)*1024 + lane*16
//   sB2  @ 28704:   128 B  b2 f32 (broadcast float4 reads)
//   sXT  @ 28832:    64 B  x_target f32
//   hcw  @ 28896 + wave*2560 + t01*1280: 16 rows x 40 bf16 (packed-b32 writes = 2/bank free)
#define SW1 16384
#define SZC 20480
#define SW2 20512
#define SB2 28704
#define SXT 28832
#define SHC 28896
#define SMEM_BYTES (28896 + 4 * 2560)   // 39136 B -> 4 blocks/CU

__device__ __forceinline__ f32x8 load8(const float* __restrict__ p) {
    float4 a = *(const float4*)p;
    float4 b = *(const float4*)(p + 4);
    f32x8 v = {a.x, a.y, a.z, a.w, b.x, b.y, b.z, b.w};
    return v;
}

__device__ __forceinline__ int pack2bf(float a, float b) {
    f32x2 v = {a, b};
    bf16x2 p = __builtin_convertvector(v, bf16x2);
    return __builtin_bit_cast(int, p);
}

__global__ __launch_bounds__(256, 4) void andp_v10(
    const float* __restrict__ x_cur,
    const float* __restrict__ W1,
    const float* __restrict__ b1,
    const float* __restrict__ W2,
    const float* __restrict__ b2,
    const float* __restrict__ Bm,
    const float* __restrict__ Cm,
    const float* __restrict__ x_t,
    float* __restrict__ out)
{
    extern __shared__ char smem[];
    int* sA2i = (int*)smem;
    int* sW1i = (int*)(smem + SW1);
    int* sW2i = (int*)(smem + SW2);
    const int tid = threadIdx.x;

    // ---- stage A2 = Bm + Cm, lane-consecutive chunk order ----
#pragma unroll
    for (int i = 0; i < 16; ++i) {
        int o2 = tid + i * 256;                 // b32 index 0..4095
        int o  = o2 * 2;                        // elem (j even)
        int kk = o >> 9, qp = (o >> 7) & 3, k = (o >> 3) & 15, j = o & 7;
        int n = 2 * kk + (qp >> 1), d = (qp & 1) * 8 + j;
        int src = n * 256 + k * 16 + d;
        float2 bv = *(const float2*)(Bm + src);
        float2 cv = *(const float2*)(Cm + src);
        sA2i[o2] = pack2bf(bv.x + cv.x, bv.y + cv.y);
    }
    // ---- stage W1 frags, lane-consecutive chunk order; + zero chunk ----
#pragma unroll
    for (int i = 0; i < 4; ++i) {
        int o2 = tid + i * 256;                 // b32 index 0..1023
        int o  = o2 * 2;                        // elem (j even)
        int t = o >> 8, qq = (o >> 7) & 1, cc = (o >> 3) & 15, j = o & 7;
        int src = (t * 16 + cc) * 16 + qq * 8 + j;
        float2 v = *(const float2*)(W1 + src);
        sW1i[o2] = pack2bf(v.x, v.y);
    }
    if (tid < 8) ((int*)(smem + SZC))[tid] = 0;
    // ---- stage W2 in permuted frag order (v9-verified) ----
#pragma unroll
    for (int i = 0; i < 8; ++i) {
        int o2 = tid + i * 256;
        int chunk = o2 >> 8, rem = o2 & 255;
        int ln = rem >> 2, j2 = rem & 3;
        int qq = ln >> 4, cc = ln & 15;
        int t2 = chunk >> 2, s = chunk & 3;
        int src = (t2 * 16 + cc) * 128 + s * 32 + 4 * qq + j2;
        sW2i[o2] = pack2bf(W2[src], W2[src + 16]);
    }
    if (tid < 32) ((float*)(smem + SB2))[tid] = b2[tid];
    if (tid < 16) ((float*)(smem + SXT))[tid] = x_t[tid];

    const int wave = tid >> 6, lane = tid & 63;
    const int c = lane & 15, q = lane >> 4;
    const int qh = q >> 1;                       // n parity for G3
    const int hh = (q & 1) * 8;                  // d-half this lane owns
    const int c4 = c * 4;

    const char* sW1f = smem + SW1;
    const int w1base = (q < 2) ? ((q * 16 + c) * 16) : (SZC - SW1);
    const int w1step = (q < 2) ? 512 : 0;
    const char* sW2f = smem + SW2 + lane * 16;   // + chunk*1024
    __bf16* hcw0 = (__bf16*)(smem + SHC + wave * 2560);
    __bf16* hcw1 = hcw0 + 640;
    const float* sB2f = (const float*)(smem + SB2);
    const float* sXTf = (const float*)(smem + SXT);

    float b1v[8];
#pragma unroll
    for (int t = 0; t < 8; ++t) b1v[t] = b1[t * 16 + c];

    __syncthreads();

    const int blk_row = blockIdx.x * 256 + wave * 64;
    const f32x4 z4 = {0.f, 0.f, 0.f, 0.f};

#pragma unroll 1
    for (int p = 0; p < 2; ++p) {
        const int r0 = blk_row + p * 32;

        // ---- x from global -> bf16 A-frag only (dif reconstructed at G3) ----
        bf16x8 af[2];
#pragma unroll
        for (int t01 = 0; t01 < 2; ++t01) {
            f32x8 xv = load8(x_cur + (size_t)(r0 + t01 * 16 + c) * 16 + hh);
            af[t01] = __builtin_convertvector(xv, bf16x8);
        }

        // ---- fused G1/G2, t01-interleaved ----
        f32x4 acc2[2][2];
        acc2[0][0] = z4; acc2[0][1] = z4; acc2[1][0] = z4; acc2[1][1] = z4;
#pragma unroll
        for (int s = 0; s < 4; ++s) {
#pragma unroll
            for (int t01 = 0; t01 < 2; ++t01) {
                __bf16* hcw = t01 ? hcw1 : hcw0;
                bf16x8 w1a = *(const bf16x8*)(sW1f + w1base + (2 * s) * w1step);
                bf16x8 w1b = *(const bf16x8*)(sW1f + w1base + (2 * s + 1) * w1step);
                f32x4 a1a = __builtin_amdgcn_mfma_f32_16x16x32_bf16(af[t01], w1a, z4, 0, 0, 0);
                f32x4 a1b = __builtin_amdgcn_mfma_f32_16x16x32_bf16(af[t01], w1b, z4, 0, 0, 0);
#pragma unroll
                for (int r = 0; r < 4; ++r) {
                    float va = fmaxf(a1a[r] + b1v[2 * s], 0.f);
                    float vb = fmaxf(a1b[r] + b1v[2 * s + 1], 0.f);
                    *(int*)(hcw + (q * 4 + r) * 40 + 2 * c) = pack2bf(va, vb);
                }
            }
#pragma unroll
            for (int t01 = 0; t01 < 2; ++t01) {
                __bf16* hcw = t01 ? hcw1 : hcw0;
                bf16x8 hb = *(const bf16x8*)(hcw + c * 40 + q * 8);
                bf16x8 w20 = *(const bf16x8*)(sW2f + (0 * 4 + s) * 1024);
                bf16x8 w21 = *(const bf16x8*)(sW2f + (1 * 4 + s) * 1024);
                acc2[t01][0] = __builtin_amdgcn_mfma_f32_16x16x32_bf16(w20, hb, acc2[t01][0], 0, 0, 0);
                acc2[t01][1] = __builtin_amdgcn_mfma_f32_16x16x32_bf16(w21, hb, acc2[t01][1], 0, 0, 0);
            }
        }

        // ---- softmax (no max-sub; b2 from LDS broadcast reads) ----
        int wq[8];
        {
            f32x4 bq0 = *(const f32x4*)(sB2f + q * 4);
            f32x4 bq1 = *(const f32x4*)(sB2f + 16 + q * 4);
#pragma unroll
            for (int t01 = 0; t01 < 2; ++t01) {
                float e[8], sum = 0.f;
#pragma unroll
                for (int r = 0; r < 4; ++r) {
                    e[r]     = __expf(acc2[t01][0][r] + bq0[r]);
                    e[4 + r] = __expf(acc2[t01][1][r] + bq1[r]);
                    sum += e[r] + e[4 + r];
                }
                sum += __shfl_xor(sum, 16, 64);
                sum += __shfl_xor(sum, 32, 64);
                float inv = 1.0f / sum;
                if (t01 == 0) {
#pragma unroll
                    for (int i = 0; i < 8; ++i) wq[i] = pack2bf(e[i] * inv, 0.f);
                } else {
#pragma unroll
                    for (int i = 0; i < 8; ++i) wq[i] |= pack2bf(0.f, e[i] * inv);
                }
            }
        }

        // ---- reconstruct dif from af (bf16 x) + LDS x_target ----
        f32x8 dif[2];
        {
            f32x4 xta = *(const f32x4*)(sXTf + hh);
            f32x4 xtb = *(const f32x4*)(sXTf + hh + 4);
            f32x8 xtv = {xta[0], xta[1], xta[2], xta[3], xtb[0], xtb[1], xtb[2], xtb[3]};
            dif[0] = xtv - __builtin_convertvector(af[0], f32x8);
            dif[1] = xtv - __builtin_convertvector(af[1], f32x8);
        }

        // ---- G3 (v8-verified gate fetch; lane-consecutive A2 chunks) ----
        f32x4 acc3[2];
        acc3[0] = z4; acc3[1] = z4;
#pragma unroll
        for (int kk = 0; kk < 16; ++kk) {
            const int lo = (kk >> 3) * 4 + 2 * (kk & 1);
            const int bpi = c4 + ((kk >> 1) & 3) * 64;
            int bpA = __builtin_amdgcn_ds_bpermute(bpi, wq[lo]);      // n = 2kk
            int bpB = __builtin_amdgcn_ds_bpermute(bpi, wq[lo + 1]);  // n = 2kk+1
            int sel = qh ? bpB : bpA;                                  // n = 2kk+qh
            float w0 = __builtin_bit_cast(float, (unsigned)sel << 16);
            float w1 = __builtin_bit_cast(float, (unsigned)sel & 0xffff0000u);
            bf16x8 a2f = *(const bf16x8*)(smem + kk * 1024 + lane * 16);
            bf16x8 g0 = __builtin_convertvector(dif[0] * w0, bf16x8);
            bf16x8 g1 = __builtin_convertvector(dif[1] * w1, bf16x8);
            acc3[0] = __builtin_amdgcn_mfma_f32_16x16x32_bf16(a2f, g0, acc3[0], 0, 0, 0);
            acc3[1] = __builtin_amdgcn_mfma_f32_16x16x32_bf16(a2f, g1, acc3[1], 0, 0, 0);
        }

        // ---- store: D[m=k_out=q*4+r][n=row=c] -> float4 per tile ----
#pragma unroll
        for (int t01 = 0; t01 < 2; ++t01) {
            float4 st = make_float4(acc3[t01][0], acc3[t01][1], acc3[t01][2], acc3[t01][3]);
            *(float4*)(out + (size_t)(r0 + t01 * 16 + c) * 16 + q * 4) = st;
        }
    }
}

extern "C" void kernel_launch(void* const* d_in, const int* in_sizes, int n_in,
                              void* d_out, int out_size, void* d_ws, size_t ws_size,
                              hipStream_t stream) {
    const float* x_cur = (const float*)d_in[0];
    const float* W1    = (const float*)d_in[1];
    const float* b1    = (const float*)d_in[2];
    const float* W2    = (const float*)d_in[3];
    const float* b2    = (const float*)d_in[4];
    const float* Bm    = (const float*)d_in[5];
    const float* Cm    = (const float*)d_in[6];
    const float* x_t   = (const float*)d_in[7];
    float* out = (float*)d_out;

    const int blocks = BATCH / 256;   // 2048 blocks x 256 rows
    andp_v10<<<blocks, 256, SMEM_BYTES, stream>>>(
        x_cur, W1, b1, W2, b2, Bm, Cm, x_t, out);
}